// Round 1
// baseline (603.083 us; speedup 1.0000x reference)
//
#include <hip/hip_runtime.h>
#include <math.h>

typedef unsigned short u16;
typedef unsigned int u32;
typedef __attribute__((ext_vector_type(8))) __bf16 bf16x8;
typedef __attribute__((ext_vector_type(4))) float f32x4;

#define DEVI __device__ __forceinline__

DEVI u16 f2bf(float f){
  u32 b = __builtin_bit_cast(u32, f);
  return (u16)((b + 0x7FFFu + ((b >> 16) & 1u)) >> 16);
}

DEVI f32x4 mfma16(bf16x8 a, bf16x8 b, f32x4 c){
  return __builtin_amdgcn_mfma_f32_16x16x32_bf16(a, b, c, 0, 0, 0);
}

// ---------------- f32 -> bf16 convert (4 elems/thread) ----------------
__global__ __launch_bounds__(256) void cvt_kernel(const float* __restrict__ in,
                                                  u16* __restrict__ out, int n4){
  int i = blockIdx.x * 256 + threadIdx.x;
  if (i >= n4) return;
  float4 v = reinterpret_cast<const float4*>(in)[i];
  u32 lo = (u32)f2bf(v.x) | ((u32)f2bf(v.y) << 16);
  u32 hi = (u32)f2bf(v.z) | ((u32)f2bf(v.w) << 16);
  reinterpret_cast<uint2*>(out)[i] = make_uint2(lo, hi);
}

// ---------------- LayerNorm: f32 in, bf16 out, row length 1024 ----------------
__global__ __launch_bounds__(256) void ln_kernel(const float* __restrict__ x,
                                                 const float* __restrict__ w,
                                                 const float* __restrict__ b,
                                                 u16* __restrict__ out){
  int row = blockIdx.x;
  int tid = threadIdx.x;
  const float4 v = reinterpret_cast<const float4*>(x + (size_t)row * 1024)[tid];
  float s  = v.x + v.y + v.z + v.w;
  float ss = v.x*v.x + v.y*v.y + v.z*v.z + v.w*v.w;
  #pragma unroll
  for (int m = 1; m < 64; m <<= 1){
    s  += __shfl_xor(s,  m, 64);
    ss += __shfl_xor(ss, m, 64);
  }
  __shared__ float red[8];
  int wid = tid >> 6, lane = tid & 63;
  if (lane == 0){ red[wid] = s; red[4 + wid] = ss; }
  __syncthreads();
  s  = red[0] + red[1] + red[2] + red[3];
  ss = red[4] + red[5] + red[6] + red[7];
  float mu   = s * (1.0f/1024.0f);
  float var  = ss * (1.0f/1024.0f) - mu*mu;
  float rstd = rsqrtf(var + 1e-5f);
  const float4 wv = reinterpret_cast<const float4*>(w)[tid];
  const float4 bv = reinterpret_cast<const float4*>(b)[tid];
  u32 lo = (u32)f2bf((v.x-mu)*rstd*wv.x + bv.x) | ((u32)f2bf((v.y-mu)*rstd*wv.y + bv.y) << 16);
  u32 hi = (u32)f2bf((v.z-mu)*rstd*wv.z + bv.z) | ((u32)f2bf((v.w-mu)*rstd*wv.w + bv.w) << 16);
  reinterpret_cast<uint2*>(out + (size_t)row*1024)[tid] = make_uint2(lo, hi);
}

// ---------------- GEMM: C(MxN) = A(MxK) * W(NxK)^T (+bias)(+relu)(+res) ----------------
// block = 256 thr (4 waves), block tile 128x128, wave tile 64x64 (4x4 MFMA 16x16x32)
template<bool HAS_BIAS, bool HAS_RES, bool RELU, bool OUT_BF16>
__global__ __launch_bounds__(256) void gemm_bt(const u16* __restrict__ A,
                                               const u16* __restrict__ W,
                                               const float* __restrict__ bias,
                                               const float* __restrict__ res,
                                               void* __restrict__ outp,
                                               int M, int N, int K){
  const int tid = threadIdx.x;
  const int wid = tid >> 6, lane = tid & 63;
  const int l16 = lane & 15, lhi = lane >> 4;
  const int row0 = blockIdx.y * 128 + (wid >> 1) * 64;
  const int col0 = blockIdx.x * 128 + (wid & 1) * 64;
  f32x4 acc[4][4] = {};
  const u16* ap[4]; const u16* wp[4];
  #pragma unroll
  for (int m = 0; m < 4; ++m) ap[m] = A + (size_t)(row0 + m*16 + l16) * K + 8*lhi;
  #pragma unroll
  for (int n = 0; n < 4; ++n) wp[n] = W + (size_t)(col0 + n*16 + l16) * K + 8*lhi;
  for (int k0 = 0; k0 < K; k0 += 32){
    bf16x8 af[4], bfr[4];
    #pragma unroll
    for (int m = 0; m < 4; ++m) af[m]  = *reinterpret_cast<const bf16x8*>(ap[m] + k0);
    #pragma unroll
    for (int n = 0; n < 4; ++n) bfr[n] = *reinterpret_cast<const bf16x8*>(wp[n] + k0);
    #pragma unroll
    for (int m = 0; m < 4; ++m){
      #pragma unroll
      for (int n = 0; n < 4; ++n){
        acc[m][n] = mfma16(af[m], bfr[n], acc[m][n]);
      }
    }
  }
  #pragma unroll
  for (int m = 0; m < 4; ++m){
    #pragma unroll
    for (int n = 0; n < 4; ++n){
      #pragma unroll
      for (int r = 0; r < 4; ++r){
        int row = row0 + m*16 + 4*lhi + r;
        int col = col0 + n*16 + l16;
        float v = acc[m][n][r];
        if constexpr (HAS_BIAS) v += bias[col];
        if constexpr (RELU)     v = fmaxf(v, 0.0f);
        if constexpr (HAS_RES)  v += res[(size_t)row * N + col];
        if constexpr (OUT_BF16) ((u16*)outp)[(size_t)row * N + col] = f2bf(v);
        else                    ((float*)outp)[(size_t)row * N + col] = v;
      }
    }
  }
}

// ---------------- causal flash attention ----------------
// qkv: (4096, 3072) bf16, per (b,t): head h occupies cols [h*192, h*192+192) = {k[0:64], q[64:128], v[128:192]}
// att: (4096, 1024) bf16, col = h*64 + d
__global__ __launch_bounds__(256) void attn_kernel(const u16* __restrict__ qkv,
                                                   u16* __restrict__ att){
  const int qt = blockIdx.x;      // q tile of 64 rows
  const int bh = blockIdx.y;
  const int bb = bh >> 4, hh = bh & 15;
  const int tid = threadIdx.x;
  const int wid = tid >> 6, lane = tid & 63;
  const int l16 = lane & 15, lhi = lane >> 4;
  const int qrow0 = qt * 64 + wid * 16;
  const u16* base = qkv + (size_t)bb * 2048 * 3072 + (size_t)hh * 192;

  bf16x8 qf[2];
  {
    const u16* qp = base + (size_t)(qrow0 + l16) * 3072 + 64 + 8*lhi;
    qf[0] = *reinterpret_cast<const bf16x8*>(qp);
    qf[1] = *reinterpret_cast<const bf16x8*>(qp + 32);
  }

  __shared__ u16 Vs[64][73];      // V tile row-major, odd pitch -> conflict-free strided reads
  __shared__ u16 Ps[4][16][72];   // per-wave P tile, pitch 72 (144B, 16B-aligned b128 reads)

  f32x4 o[4] = {};
  float m_r[4], l_r[4];
  #pragma unroll
  for (int r = 0; r < 4; ++r){ m_r[r] = -INFINITY; l_r[r] = 0.0f; }

  const int nkt = qt + 1;
  for (int kt = 0; kt < nkt; ++kt){
    const int kb = kt * 64;
    __syncthreads();
    // stage V tile (64x64) row-major, coalesced uint2 loads
    #pragma unroll
    for (int it = 0; it < 4; ++it){
      int e  = tid + 256 * it;     // 0..1023
      int vr = e >> 4;             // 0..63
      int c0 = (e & 15) * 4;       // 0..60
      const u16* src = base + (size_t)(kb + vr) * 3072 + 128 + c0;
      uint2 d = *reinterpret_cast<const uint2*>(src);
      Vs[vr][c0+0] = (u16)(d.x);
      Vs[vr][c0+1] = (u16)(d.x >> 16);
      Vs[vr][c0+2] = (u16)(d.y);
      Vs[vr][c0+3] = (u16)(d.y >> 16);
    }
    __syncthreads();

    // S = (Q K^T) * 0.125
    f32x4 s_acc[4] = {};
    #pragma unroll
    for (int f = 0; f < 4; ++f){
      const u16* kp = base + (size_t)(kb + f*16 + l16) * 3072 + 8*lhi;
      bf16x8 k0 = *reinterpret_cast<const bf16x8*>(kp);
      bf16x8 k1 = *reinterpret_cast<const bf16x8*>(kp + 32);
      s_acc[f] = mfma16(qf[0], k0, s_acc[f]);
      s_acc[f] = mfma16(qf[1], k1, s_acc[f]);
    }

    float sc[4][4];
    #pragma unroll
    for (int f = 0; f < 4; ++f){
      #pragma unroll
      for (int r = 0; r < 4; ++r) sc[f][r] = s_acc[f][r] * 0.125f;
    }

    if (kt == nkt - 1){           // diagonal tile: causal mask
      #pragma unroll
      for (int f = 0; f < 4; ++f){
        int col = kb + f*16 + l16;
        #pragma unroll
        for (int r = 0; r < 4; ++r){
          int row = qrow0 + 4*lhi + r;
          if (col > row) sc[f][r] = -INFINITY;
        }
      }
    }

    // online softmax (rows live in 16-lane groups)
    float alpha[4], p[4][4];
    #pragma unroll
    for (int r = 0; r < 4; ++r){
      float mx = fmaxf(fmaxf(sc[0][r], sc[1][r]), fmaxf(sc[2][r], sc[3][r]));
      #pragma unroll
      for (int m = 1; m < 16; m <<= 1) mx = fmaxf(mx, __shfl_xor(mx, m, 64));
      float mnew = fmaxf(m_r[r], mx);
      alpha[r] = __expf(m_r[r] - mnew);
      m_r[r] = mnew;
      float sum = 0.0f;
      #pragma unroll
      for (int f = 0; f < 4; ++f){ p[f][r] = __expf(sc[f][r] - mnew); sum += p[f][r]; }
      #pragma unroll
      for (int m = 1; m < 16; m <<= 1) sum += __shfl_xor(sum, m, 64);
      l_r[r] = l_r[r] * alpha[r] + sum;
    }
    #pragma unroll
    for (int n = 0; n < 4; ++n){
      #pragma unroll
      for (int r = 0; r < 4; ++r) o[n][r] *= alpha[r];
    }

    // P (D-layout) -> per-wave LDS as bf16
    #pragma unroll
    for (int f = 0; f < 4; ++f){
      #pragma unroll
      for (int r = 0; r < 4; ++r)
        Ps[wid][4*lhi + r][f*16 + l16] = f2bf(p[f][r]);
    }

    // P as A-fragments (compiler inserts lgkmcnt for same-wave LDS RAW)
    bf16x8 pa[2];
    pa[0] = *reinterpret_cast<const bf16x8*>(&Ps[wid][l16][8*lhi]);
    pa[1] = *reinterpret_cast<const bf16x8*>(&Ps[wid][l16][8*lhi + 32]);

    // V^T fragments via strided scalar LDS reads, then PV MFMA
    #pragma unroll
    for (int n = 0; n < 4; ++n){
      #pragma unroll
      for (int s = 0; s < 2; ++s){
        int vr = 8*lhi + 32*s;
        int vc = n*16 + l16;
        u32 w0 = (u32)Vs[vr+0][vc] | ((u32)Vs[vr+1][vc] << 16);
        u32 w1 = (u32)Vs[vr+2][vc] | ((u32)Vs[vr+3][vc] << 16);
        u32 w2 = (u32)Vs[vr+4][vc] | ((u32)Vs[vr+5][vc] << 16);
        u32 w3 = (u32)Vs[vr+6][vc] | ((u32)Vs[vr+7][vc] << 16);
        bf16x8 vb = __builtin_bit_cast(bf16x8, make_uint4(w0, w1, w2, w3));
        o[n] = mfma16(pa[s], vb, o[n]);
      }
    }
  }

  #pragma unroll
  for (int r = 0; r < 4; ++r) l_r[r] = 1.0f / l_r[r];
  #pragma unroll
  for (int n = 0; n < 4; ++n){
    #pragma unroll
    for (int r = 0; r < 4; ++r){
      int row = qrow0 + 4*lhi + r;
      int col = hh*64 + n*16 + l16;
      att[(size_t)(bb*2048 + row) * 1024 + col] = f2bf(o[n][r] * l_r[r]);
    }
  }
}

extern "C" void kernel_launch(void* const* d_in, const int* in_sizes, int n_in,
                              void* d_out, int out_size, void* d_ws, size_t ws_size,
                              hipStream_t stream){
  const float* x        = (const float*)d_in[0];
  const float* ln1_w    = (const float*)d_in[1];
  const float* ln1_b    = (const float*)d_in[2];
  const float* c_proj_w = (const float*)d_in[3];
  const float* proj_w   = (const float*)d_in[4];
  const float* proj_b   = (const float*)d_in[5];
  const float* ln2_w    = (const float*)d_in[6];
  const float* ln2_b    = (const float*)d_in[7];
  const float* ffn1_w   = (const float*)d_in[8];
  const float* ffn1_b   = (const float*)d_in[9];
  const float* ffn2_w   = (const float*)d_in[10];
  const float* ffn2_b   = (const float*)d_in[11];

  char* p = (char*)d_ws;
  u16* Wqkv  = (u16*)p;  p += (size_t)3072*1024*2;   // 6.0 MiB
  u16* Wproj = (u16*)p;  p += (size_t)1024*1024*2;   // 2.0 MiB
  u16* Wff1  = (u16*)p;  p += (size_t)4096*1024*2;   // 8.0 MiB
  u16* Wff2  = (u16*)p;  p += (size_t)1024*4096*2;   // 8.0 MiB
  u16* LNb   = (u16*)p;  p += (size_t)4096*1024*2;   // 8.0 MiB (ln1 out, reused for ln2 out)
  u16* QKV   = (u16*)p;  p += (size_t)4096*3072*2;   // 24 MiB
  u16* ATT   = (u16*)p;  p += (size_t)4096*1024*2;   // 8.0 MiB
  float* ACT2= (float*)p;                            // 16 MiB  (total 80 MiB)
  u16* FFN1  = QKV;      // reuse QKV+ATT region (exactly 32 MiB) after attention+proj

  // weight pre-conversion to bf16
  cvt_kernel<<<3072, 256, 0, stream>>>(c_proj_w, Wqkv, 786432);
  cvt_kernel<<<1024, 256, 0, stream>>>(proj_w,  Wproj, 262144);
  cvt_kernel<<<4096, 256, 0, stream>>>(ffn1_w,  Wff1, 1048576);
  cvt_kernel<<<4096, 256, 0, stream>>>(ffn2_w,  Wff2, 1048576);

  // ln1 -> qkv -> attn -> proj(+x) -> ln2 -> ffn1(relu) -> ffn2(+x) = out
  ln_kernel<<<4096, 256, 0, stream>>>(x, ln1_w, ln1_b, LNb);
  gemm_bt<false,false,false,true ><<<dim3(24,32), 256, 0, stream>>>(LNb, Wqkv, nullptr, nullptr, QKV, 4096, 3072, 1024);
  attn_kernel<<<dim3(32,32), 256, 0, stream>>>(QKV, ATT);
  gemm_bt<true ,true ,false,false><<<dim3(8,32),  256, 0, stream>>>(ATT, Wproj, proj_b, x, ACT2, 4096, 1024, 1024);
  ln_kernel<<<4096, 256, 0, stream>>>(ACT2, ln2_w, ln2_b, LNb);
  gemm_bt<true ,false,true ,true ><<<dim3(32,32), 256, 0, stream>>>(LNb, Wff1, ffn1_b, nullptr, FFN1, 4096, 4096, 1024);
  gemm_bt<true ,true ,false,false><<<dim3(8,32),  256, 0, stream>>>(FFN1, Wff2, ffn2_b, x, (float*)d_out, 4096, 1024, 4096);
}

// Round 3
// 382.427 us; speedup vs baseline: 1.5770x; 1.5770x over previous
//
#include <hip/hip_runtime.h>
#include <math.h>

typedef unsigned short u16;
typedef unsigned int u32;
typedef __attribute__((ext_vector_type(8))) __bf16 bf16x8;
typedef __attribute__((ext_vector_type(4))) float f32x4;

#define DEVI __device__ __forceinline__

DEVI u16 f2bf(float f){
  u32 b = __builtin_bit_cast(u32, f);
  return (u16)((b + 0x7FFFu + ((b >> 16) & 1u)) >> 16);
}

DEVI f32x4 mfma16(bf16x8 a, bf16x8 b, f32x4 c){
  return __builtin_amdgcn_mfma_f32_16x16x32_bf16(a, b, c, 0, 0, 0);
}

// async global->LDS, 16B per lane; LDS dest = wave-uniform base + lane*16.
// Proper address-space casts (no integer truncation round-trip).
DEVI void gload16(const u16* g, u16* l){
  __builtin_amdgcn_global_load_lds(
      (const __attribute__((address_space(1))) u32*)g,
      (__attribute__((address_space(3))) u32*)l,
      16, 0, 0);
}

// ---------------- f32 -> bf16 convert (4 elems/thread) ----------------
__global__ __launch_bounds__(256) void cvt_kernel(const float* __restrict__ in,
                                                  u16* __restrict__ out, int n4){
  int i = blockIdx.x * 256 + threadIdx.x;
  if (i >= n4) return;
  float4 v = reinterpret_cast<const float4*>(in)[i];
  u32 lo = (u32)f2bf(v.x) | ((u32)f2bf(v.y) << 16);
  u32 hi = (u32)f2bf(v.z) | ((u32)f2bf(v.w) << 16);
  reinterpret_cast<uint2*>(out)[i] = make_uint2(lo, hi);
}

// ---------------- LayerNorm: f32 in, bf16 out, row length 1024 ----------------
__global__ __launch_bounds__(256) void ln_kernel(const float* __restrict__ x,
                                                 const float* __restrict__ w,
                                                 const float* __restrict__ b,
                                                 u16* __restrict__ out){
  int row = blockIdx.x;
  int tid = threadIdx.x;
  const float4 v = reinterpret_cast<const float4*>(x + (size_t)row * 1024)[tid];
  float s  = v.x + v.y + v.z + v.w;
  float ss = v.x*v.x + v.y*v.y + v.z*v.z + v.w*v.w;
  #pragma unroll
  for (int m = 1; m < 64; m <<= 1){
    s  += __shfl_xor(s,  m, 64);
    ss += __shfl_xor(ss, m, 64);
  }
  __shared__ float red[8];
  int wid = tid >> 6, lane = tid & 63;
  if (lane == 0){ red[wid] = s; red[4 + wid] = ss; }
  __syncthreads();
  s  = red[0] + red[1] + red[2] + red[3];
  ss = red[4] + red[5] + red[6] + red[7];
  float mu   = s * (1.0f/1024.0f);
  float var  = ss * (1.0f/1024.0f) - mu*mu;
  float rstd = rsqrtf(var + 1e-5f);
  const float4 wv = reinterpret_cast<const float4*>(w)[tid];
  const float4 bv = reinterpret_cast<const float4*>(b)[tid];
  u32 lo = (u32)f2bf((v.x-mu)*rstd*wv.x + bv.x) | ((u32)f2bf((v.y-mu)*rstd*wv.y + bv.y) << 16);
  u32 hi = (u32)f2bf((v.z-mu)*rstd*wv.z + bv.z) | ((u32)f2bf((v.w-mu)*rstd*wv.w + bv.w) << 16);
  reinterpret_cast<uint2*>(out + (size_t)row*1024)[tid] = make_uint2(lo, hi);
}

// ---------------- GEMM (m97 structure): C(MxN) = A(MxK) * W(NxK)^T ----------------
// 256 thr / 4 waves, block tile 128x128, wave tile 64x64, BK=32,
// global_load_lds(16B) staging into linear LDS [128][32], 2 barriers per K-step.
template<bool HAS_BIAS, bool HAS_RES, bool RELU, bool OUT_BF16>
__global__ __launch_bounds__(256) void gemm_bt(const u16* __restrict__ A,
                                               const u16* __restrict__ W,
                                               const float* __restrict__ bias,
                                               const float* __restrict__ res,
                                               void* __restrict__ outp,
                                               int M, int N, int K){
  const int tid = threadIdx.x;
  const int wid = tid >> 6, lane = tid & 63;
  const int l16 = lane & 15, lhi = lane >> 4;
  const int wr = wid >> 1, wc = wid & 1;
  const int brow = blockIdx.y * 128;
  const int bcol = blockIdx.x * 128;

  __shared__ u16 As[128*32];   // linear row-major, 64B rows
  __shared__ u16 Bs[128*32];

  // staging: wave w loads A rows [w*32, w*32+32) and W rows [w*32, w*32+32)
  // each global_load_lds covers 16 rows: lane l -> row l>>2, 16B chunk l&3
  const int srow = wid*32 + (lane >> 2);
  const int schk = lane & 3;
  const u16* gA0 = A + (size_t)(brow + srow)      * K + schk*8;
  const u16* gA1 = A + (size_t)(brow + srow + 16) * K + schk*8;
  const u16* gW0 = W + (size_t)(bcol + srow)      * K + schk*8;
  const u16* gW1 = W + (size_t)(bcol + srow + 16) * K + schk*8;
  u16* lA0 = &As[(wid*32)*32];
  u16* lA1 = &As[(wid*32 + 16)*32];
  u16* lB0 = &Bs[(wid*32)*32];
  u16* lB1 = &Bs[(wid*32 + 16)*32];

  f32x4 acc[4][4] = {};

  for (int k0 = 0; k0 < K; k0 += 32){
    __syncthreads();               // previous compute's LDS reads done
    gload16(gA0 + k0, lA0);
    gload16(gA1 + k0, lA1);
    gload16(gW0 + k0, lB0);
    gload16(gW1 + k0, lB1);
    __syncthreads();               // staging drained (vmcnt(0) at barrier)
    bf16x8 af[4], bfr[4];
    #pragma unroll
    for (int m = 0; m < 4; ++m)
      af[m]  = *reinterpret_cast<const bf16x8*>(&As[(wr*64 + m*16 + l16)*32 + 8*lhi]);
    #pragma unroll
    for (int n = 0; n < 4; ++n)
      bfr[n] = *reinterpret_cast<const bf16x8*>(&Bs[(wc*64 + n*16 + l16)*32 + 8*lhi]);
    #pragma unroll
    for (int m = 0; m < 4; ++m){
      #pragma unroll
      for (int n = 0; n < 4; ++n){
        acc[m][n] = mfma16(af[m], bfr[n], acc[m][n]);
      }
    }
  }

  const int row0 = brow + wr*64;
  const int col0 = bcol + wc*64;
  #pragma unroll
  for (int m = 0; m < 4; ++m){
    #pragma unroll
    for (int n = 0; n < 4; ++n){
      #pragma unroll
      for (int r = 0; r < 4; ++r){
        int row = row0 + m*16 + 4*lhi + r;
        int col = col0 + n*16 + l16;
        float v = acc[m][n][r];
        if constexpr (HAS_BIAS) v += bias[col];
        if constexpr (RELU)     v = fmaxf(v, 0.0f);
        if constexpr (HAS_RES)  v += res[(size_t)row * N + col];
        if constexpr (OUT_BF16) ((u16*)outp)[(size_t)row * N + col] = f2bf(v);
        else                    ((float*)outp)[(size_t)row * N + col] = v;
      }
    }
  }
}

// ---------------- causal flash attention ----------------
// qkv: (4096, 3072) bf16; head h cols [h*192, h*192+192) = {k[0:64], q[64:128], v[128:192]}
// K staged row-major (pitch 72), V staged TRANSPOSED Vt[d][k] (pitch 72).
// Per tile (64x64 each of K and V): 256 threads x (2+2) uint4 = full 16 KB coverage.
__global__ __launch_bounds__(256) void attn_kernel(const u16* __restrict__ qkv,
                                                   u16* __restrict__ att){
  const int qt = 31 - blockIdx.x;       // heavy tiles first (LPT) to kill tail
  const int bh = blockIdx.y;
  const int bb = bh >> 4, hh = bh & 15;
  const int tid = threadIdx.x;
  const int wid = tid >> 6, lane = tid & 63;
  const int l16 = lane & 15, lhi = lane >> 4;
  const int qrow0 = qt * 64 + wid * 16;
  const u16* base = qkv + (size_t)bb * 2048 * 3072 + (size_t)hh * 192;

  __shared__ u16 Ks[64*72];     // K tile row-major [k][d], pitch 72
  __shared__ u16 Vt[64*72];     // V tile transposed [d][k], pitch 72
  __shared__ u16 Ps[4*16*72];   // per-wave P tile, pitch 72

  bf16x8 qf[2];
  {
    const u16* qp = base + (size_t)(qrow0 + l16) * 3072 + 64 + 8*lhi;
    qf[0] = *reinterpret_cast<const bf16x8*>(qp);
    qf[1] = *reinterpret_cast<const bf16x8*>(qp + 32);
  }

  f32x4 o[4] = {};
  float m_r[4], l_r[4];
  #pragma unroll
  for (int r = 0; r < 4; ++r){ m_r[r] = -INFINITY; l_r[r] = 0.0f; }

  // staging assignment: thread -> row sr (0..63), chunks sc and sc+4 (8 u16 each)
  const int sr = tid >> 2;
  const int sc = tid & 3;
  const u16* stage_base = base + (size_t)sr * 3072 + sc*8;

  const int nkt = qt + 1;
  for (int kt = 0; kt < nkt; ++kt){
    const int kb = kt * 64;
    const u16* srow = stage_base + (size_t)kb * 3072;
    uint4 kd0 = *reinterpret_cast<const uint4*>(srow);          // K[sr][sc*8 .. +7]
    uint4 kd1 = *reinterpret_cast<const uint4*>(srow + 32);     // K[sr][sc*8+32 .. +7]
    uint4 vd0 = *reinterpret_cast<const uint4*>(srow + 128);    // V[sr][sc*8 .. +7]
    uint4 vd1 = *reinterpret_cast<const uint4*>(srow + 160);    // V[sr][sc*8+32 .. +7]
    __syncthreads();             // previous iteration's LDS reads done
    *reinterpret_cast<uint4*>(&Ks[sr*72 + sc*8])      = kd0;
    *reinterpret_cast<uint4*>(&Ks[sr*72 + sc*8 + 32]) = kd1;
    {
      u32 w0[4] = {vd0.x, vd0.y, vd0.z, vd0.w};
      u32 w1[4] = {vd1.x, vd1.y, vd1.z, vd1.w};
      #pragma unroll
      for (int j = 0; j < 8; ++j){
        Vt[(sc*8 + j)*72 + sr]      = (u16)(w0[j>>1] >> (16*(j&1)));
        Vt[(sc*8 + 32 + j)*72 + sr] = (u16)(w1[j>>1] >> (16*(j&1)));
      }
    }
    __syncthreads();             // tile staged

    // S = (Q K^T) * 0.125
    f32x4 s_acc[4] = {};
    #pragma unroll
    for (int f = 0; f < 4; ++f){
      const u16* kp = &Ks[(f*16 + l16)*72 + 8*lhi];
      bf16x8 k0 = *reinterpret_cast<const bf16x8*>(kp);
      bf16x8 k1 = *reinterpret_cast<const bf16x8*>(kp + 32);
      s_acc[f] = mfma16(qf[0], k0, s_acc[f]);
      s_acc[f] = mfma16(qf[1], k1, s_acc[f]);
    }

    float sc_[4][4];
    #pragma unroll
    for (int f = 0; f < 4; ++f){
      #pragma unroll
      for (int r = 0; r < 4; ++r) sc_[f][r] = s_acc[f][r] * 0.125f;
    }

    if (kt == nkt - 1){          // diagonal tile: causal mask
      #pragma unroll
      for (int f = 0; f < 4; ++f){
        int col = kb + f*16 + l16;
        #pragma unroll
        for (int r = 0; r < 4; ++r){
          int row = qrow0 + 4*lhi + r;
          if (col > row) sc_[f][r] = -INFINITY;
        }
      }
    }

    // online softmax (rows live in 16-lane groups)
    float alpha[4], p[4][4];
    #pragma unroll
    for (int r = 0; r < 4; ++r){
      float mx = fmaxf(fmaxf(sc_[0][r], sc_[1][r]), fmaxf(sc_[2][r], sc_[3][r]));
      #pragma unroll
      for (int m = 1; m < 16; m <<= 1) mx = fmaxf(mx, __shfl_xor(mx, m, 64));
      float mnew = fmaxf(m_r[r], mx);
      alpha[r] = __expf(m_r[r] - mnew);
      m_r[r] = mnew;
      float sum = 0.0f;
      #pragma unroll
      for (int f = 0; f < 4; ++f){ p[f][r] = __expf(sc_[f][r] - mnew); sum += p[f][r]; }
      #pragma unroll
      for (int m = 1; m < 16; m <<= 1) sum += __shfl_xor(sum, m, 64);
      l_r[r] = l_r[r] * alpha[r] + sum;
    }
    #pragma unroll
    for (int n = 0; n < 4; ++n){
      #pragma unroll
      for (int r = 0; r < 4; ++r) o[n][r] *= alpha[r];
    }

    // P (D-layout) -> per-wave LDS as bf16, read back as A-fragments
    #pragma unroll
    for (int f = 0; f < 4; ++f){
      #pragma unroll
      for (int r = 0; r < 4; ++r)
        Ps[wid*1152 + (4*lhi + r)*72 + f*16 + l16] = f2bf(p[f][r]);
    }
    bf16x8 pa[2];
    pa[0] = *reinterpret_cast<const bf16x8*>(&Ps[wid*1152 + l16*72 + 8*lhi]);
    pa[1] = *reinterpret_cast<const bf16x8*>(&Ps[wid*1152 + l16*72 + 8*lhi + 32]);

    // PV: B-fragments are contiguous b128 reads from transposed V
    #pragma unroll
    for (int n = 0; n < 4; ++n){
      #pragma unroll
      for (int s = 0; s < 2; ++s){
        bf16x8 vb = *reinterpret_cast<const bf16x8*>(&Vt[(n*16 + l16)*72 + 8*lhi + 32*s]);
        o[n] = mfma16(pa[s], vb, o[n]);
      }
    }
  }

  #pragma unroll
  for (int r = 0; r < 4; ++r) l_r[r] = 1.0f / l_r[r];
  #pragma unroll
  for (int n = 0; n < 4; ++n){
    #pragma unroll
    for (int r = 0; r < 4; ++r){
      int row = qrow0 + 4*lhi + r;
      int col = hh*64 + n*16 + l16;
      att[(size_t)(bb*2048 + row) * 1024 + col] = f2bf(o[n][r] * l_r[r]);
    }
  }
}

extern "C" void kernel_launch(void* const* d_in, const int* in_sizes, int n_in,
                              void* d_out, int out_size, void* d_ws, size_t ws_size,
                              hipStream_t stream){
  const float* x        = (const float*)d_in[0];
  const float* ln1_w    = (const float*)d_in[1];
  const float* ln1_b    = (const float*)d_in[2];
  const float* c_proj_w = (const float*)d_in[3];
  const float* proj_w   = (const float*)d_in[4];
  const float* proj_b   = (const float*)d_in[5];
  const float* ln2_w    = (const float*)d_in[6];
  const float* ln2_b    = (const float*)d_in[7];
  const float* ffn1_w   = (const float*)d_in[8];
  const float* ffn1_b   = (const float*)d_in[9];
  const float* ffn2_w   = (const float*)d_in[10];
  const float* ffn2_b   = (const float*)d_in[11];

  char* p = (char*)d_ws;
  u16* Wqkv  = (u16*)p;  p += (size_t)3072*1024*2;   // 6.0 MiB
  u16* Wproj = (u16*)p;  p += (size_t)1024*1024*2;   // 2.0 MiB
  u16* Wff1  = (u16*)p;  p += (size_t)4096*1024*2;   // 8.0 MiB
  u16* Wff2  = (u16*)p;  p += (size_t)1024*4096*2;   // 8.0 MiB
  u16* LNb   = (u16*)p;  p += (size_t)4096*1024*2;   // 8.0 MiB (ln1 out, reused for ln2 out)
  u16* QKV   = (u16*)p;  p += (size_t)4096*3072*2;   // 24 MiB
  u16* ATT   = (u16*)p;  p += (size_t)4096*1024*2;   // 8.0 MiB
  float* ACT2= (float*)p;                            // 16 MiB  (total 80 MiB)
  u16* FFN1  = QKV;      // reuse QKV+ATT region (32 MiB) after attention+proj

  // weight pre-conversion to bf16
  cvt_kernel<<<3072, 256, 0, stream>>>(c_proj_w, Wqkv, 786432);
  cvt_kernel<<<1024, 256, 0, stream>>>(proj_w,  Wproj, 262144);
  cvt_kernel<<<4096, 256, 0, stream>>>(ffn1_w,  Wff1, 1048576);
  cvt_kernel<<<4096, 256, 0, stream>>>(ffn2_w,  Wff2, 1048576);

  // ln1 -> qkv -> attn -> proj(+x) -> ln2 -> ffn1(relu) -> ffn2(+x) = out
  ln_kernel<<<4096, 256, 0, stream>>>(x, ln1_w, ln1_b, LNb);
  gemm_bt<false,false,false,true ><<<dim3(24,32), 256, 0, stream>>>(LNb, Wqkv, nullptr, nullptr, QKV, 4096, 3072, 1024);
  attn_kernel<<<dim3(32,32), 256, 0, stream>>>(QKV, ATT);
  gemm_bt<true ,true ,false,false><<<dim3(8,32),  256, 0, stream>>>(ATT, Wproj, proj_b, x, ACT2, 4096, 1024, 1024);
  ln_kernel<<<4096, 256, 0, stream>>>(ACT2, ln2_w, ln2_b, LNb);
  gemm_bt<true ,false,true ,true ><<<dim3(32,32), 256, 0, stream>>>(LNb, Wff1, ffn1_b, nullptr, FFN1, 4096, 4096, 1024);
  gemm_bt<true ,true ,false,false><<<dim3(8,32),  256, 0, stream>>>(FFN1, Wff2, ffn2_b, x, (float*)d_out, 4096, 1024, 4096);
}

// Round 6
// 313.200 us; speedup vs baseline: 1.9256x; 1.2210x over previous
//
#include <hip/hip_runtime.h>
#include <math.h>

typedef unsigned short u16;
typedef unsigned int u32;
typedef __attribute__((ext_vector_type(8))) __bf16 bf16x8;
typedef __attribute__((ext_vector_type(4))) float f32x4;

#define DEVI __device__ __forceinline__

DEVI u16 f2bf(float f){
  u32 b = __builtin_bit_cast(u32, f);
  return (u16)((b + 0x7FFFu + ((b >> 16) & 1u)) >> 16);
}

DEVI f32x4 mfma16(bf16x8 a, bf16x8 b, f32x4 c){
  return __builtin_amdgcn_mfma_f32_16x16x32_bf16(a, b, c, 0, 0, 0);
}

// async global->LDS, 16B per lane; LDS dest = wave-uniform base + lane*16.
DEVI void gload16(const u16* g, u16* l){
  __builtin_amdgcn_global_load_lds(
      (const __attribute__((address_space(1))) u32*)g,
      (__attribute__((address_space(3))) u32*)l,
      16, 0, 0);
}

// ---------------- f32 -> bf16 convert (4 elems/thread) ----------------
__global__ __launch_bounds__(256) void cvt_kernel(const float* __restrict__ in,
                                                  u16* __restrict__ out, int n4){
  int i = blockIdx.x * 256 + threadIdx.x;
  if (i >= n4) return;
  float4 v = reinterpret_cast<const float4*>(in)[i];
  u32 lo = (u32)f2bf(v.x) | ((u32)f2bf(v.y) << 16);
  u32 hi = (u32)f2bf(v.z) | ((u32)f2bf(v.w) << 16);
  reinterpret_cast<uint2*>(out)[i] = make_uint2(lo, hi);
}

// ---------------- LayerNorm: f32 in, bf16 out, row length 1024 ----------------
__global__ __launch_bounds__(256) void ln_kernel(const float* __restrict__ x,
                                                 const float* __restrict__ w,
                                                 const float* __restrict__ b,
                                                 u16* __restrict__ out){
  int row = blockIdx.x;
  int tid = threadIdx.x;
  const float4 v = reinterpret_cast<const float4*>(x + (size_t)row * 1024)[tid];
  float s  = v.x + v.y + v.z + v.w;
  float ss = v.x*v.x + v.y*v.y + v.z*v.z + v.w*v.w;
  #pragma unroll
  for (int m = 1; m < 64; m <<= 1){
    s  += __shfl_xor(s,  m, 64);
    ss += __shfl_xor(ss, m, 64);
  }
  __shared__ float red[8];
  int wid = tid >> 6, lane = tid & 63;
  if (lane == 0){ red[wid] = s; red[4 + wid] = ss; }
  __syncthreads();
  s  = red[0] + red[1] + red[2] + red[3];
  ss = red[4] + red[5] + red[6] + red[7];
  float mu   = s * (1.0f/1024.0f);
  float var  = ss * (1.0f/1024.0f) - mu*mu;
  float rstd = rsqrtf(var + 1e-5f);
  const float4 wv = reinterpret_cast<const float4*>(w)[tid];
  const float4 bv = reinterpret_cast<const float4*>(b)[tid];
  u32 lo = (u32)f2bf((v.x-mu)*rstd*wv.x + bv.x) | ((u32)f2bf((v.y-mu)*rstd*wv.y + bv.y) << 16);
  u32 hi = (u32)f2bf((v.z-mu)*rstd*wv.z + bv.z) | ((u32)f2bf((v.w-mu)*rstd*wv.w + bv.w) << 16);
  reinterpret_cast<uint2*>(out + (size_t)row*1024)[tid] = make_uint2(lo, hi);
}

// ---------------- GEMM (m97 structure): C(MxN) = A(MxK) * W(NxK)^T ----------------
template<bool HAS_BIAS, bool HAS_RES, bool RELU, bool OUT_BF16>
__global__ __launch_bounds__(256) void gemm_bt(const u16* __restrict__ A,
                                               const u16* __restrict__ W,
                                               const float* __restrict__ bias,
                                               const float* __restrict__ res,
                                               void* __restrict__ outp,
                                               int M, int N, int K){
  const int tid = threadIdx.x;
  const int wid = tid >> 6, lane = tid & 63;
  const int l16 = lane & 15, lhi = lane >> 4;
  const int wr = wid >> 1, wc = wid & 1;
  const int brow = blockIdx.y * 128;
  const int bcol = blockIdx.x * 128;

  __shared__ u16 As[128*32];
  __shared__ u16 Bs[128*32];

  const int srow = wid*32 + (lane >> 2);
  const int schk = lane & 3;
  const u16* gA0 = A + (size_t)(brow + srow)      * K + schk*8;
  const u16* gA1 = A + (size_t)(brow + srow + 16) * K + schk*8;
  const u16* gW0 = W + (size_t)(bcol + srow)      * K + schk*8;
  const u16* gW1 = W + (size_t)(bcol + srow + 16) * K + schk*8;
  u16* lA0 = &As[(wid*32)*32];
  u16* lA1 = &As[(wid*32 + 16)*32];
  u16* lB0 = &Bs[(wid*32)*32];
  u16* lB1 = &Bs[(wid*32 + 16)*32];

  f32x4 acc[4][4] = {};

  for (int k0 = 0; k0 < K; k0 += 32){
    __syncthreads();
    gload16(gA0 + k0, lA0);
    gload16(gA1 + k0, lA1);
    gload16(gW0 + k0, lB0);
    gload16(gW1 + k0, lB1);
    __syncthreads();
    bf16x8 af[4], bfr[4];
    #pragma unroll
    for (int m = 0; m < 4; ++m)
      af[m]  = *reinterpret_cast<const bf16x8*>(&As[(wr*64 + m*16 + l16)*32 + 8*lhi]);
    #pragma unroll
    for (int n = 0; n < 4; ++n)
      bfr[n] = *reinterpret_cast<const bf16x8*>(&Bs[(wc*64 + n*16 + l16)*32 + 8*lhi]);
    #pragma unroll
    for (int m = 0; m < 4; ++m){
      #pragma unroll
      for (int n = 0; n < 4; ++n){
        acc[m][n] = mfma16(af[m], bfr[n], acc[m][n]);
      }
    }
  }

  const int row0 = brow + wr*64;
  const int col0 = bcol + wc*64;
  #pragma unroll
  for (int m = 0; m < 4; ++m){
    #pragma unroll
    for (int n = 0; n < 4; ++n){
      #pragma unroll
      for (int r = 0; r < 4; ++r){
        int row = row0 + m*16 + 4*lhi + r;
        int col = col0 + n*16 + l16;
        float v = acc[m][n][r];
        if constexpr (HAS_BIAS) v += bias[col];
        if constexpr (RELU)     v = fmaxf(v, 0.0f);
        if constexpr (HAS_RES)  v += res[(size_t)row * N + col];
        if constexpr (OUT_BF16) ((u16*)outp)[(size_t)row * N + col] = f2bf(v);
        else                    ((float*)outp)[(size_t)row * N + col] = v;
      }
    }
  }
}

// ---------------- causal flash attention (paired LPT + prefetch, R3 dataflow) -------
// qkv: (4096, 3072) bf16; head h cols [h*192,+192) = {k[0:64], q[64:128], v[128:192]}
// K LDS: row-major [k][d], pitch 72 (reads conflict-free).
// V LDS: transposed Vt[d][k], pitch 72, chunk-XOR swizzle on k:
//   element (d,k) at d*72 + (((k>>3)^(d>>3))<<3) + (k&7)
//   -> scalar writes spread banks (2-way), b128 reads stay conflict-free, 16B-aligned.
// P LDS: per-wave row-major [q][k], pitch 72 (R3-proven).
__global__ __launch_bounds__(256) void attn_kernel(const u16* __restrict__ qkv,
                                                   u16* __restrict__ att){
  const int bx = blockIdx.x;            // handles qt = bx and 31-bx (33 tiles total)
  const int bh = blockIdx.y;
  const int bb = bh >> 4, hh = bh & 15;
  const int tid = threadIdx.x;
  const int wid = tid >> 6, lane = tid & 63;
  const int l16 = lane & 15, lhi = lane >> 4;
  const u16* base = qkv + (size_t)bb * 2048 * 3072 + (size_t)hh * 192;

  __shared__ u16 Ks[64*72];     // 9216 B
  __shared__ u16 Vt[64*72];     // 9216 B
  __shared__ u16 Ps[4*16*72];   // 9216 B

  // staging assignment: thread -> row sr (0..63), chunks sc and sc+4 (8 u16 each)
  const int sr = tid >> 2;
  const int sc = tid & 3;
  const u16* stage_base = base + (size_t)sr * 3072 + sc*8;   // K at +0, V at +128

  for (int ph = 0; ph < 2; ++ph){
    const int qt = ph ? (31 - bx) : bx;
    const int qrow0 = qt * 64 + wid * 16;

    bf16x8 qf[2];
    {
      const u16* qp = base + (size_t)(qrow0 + l16) * 3072 + 64 + 8*lhi;
      qf[0] = *reinterpret_cast<const bf16x8*>(qp);
      qf[1] = *reinterpret_cast<const bf16x8*>(qp + 32);
    }

    f32x4 o[4] = {};
    float m_r[4], l_r[4];
    #pragma unroll
    for (int r = 0; r < 4; ++r){ m_r[r] = -INFINITY; l_r[r] = 0.0f; }

    const int nkt = qt + 1;

    // prologue: load tile 0 into regs
    uint4 kd0, kd1, vd0, vd1;
    {
      const u16* srow = stage_base;
      kd0 = *reinterpret_cast<const uint4*>(srow);
      kd1 = *reinterpret_cast<const uint4*>(srow + 32);
      vd0 = *reinterpret_cast<const uint4*>(srow + 128);
      vd1 = *reinterpret_cast<const uint4*>(srow + 160);
    }

    for (int kt = 0; kt < nkt; ++kt){
      __syncthreads();             // all waves done reading previous tile
      *reinterpret_cast<uint4*>(&Ks[sr*72 + sc*8])      = kd0;
      *reinterpret_cast<uint4*>(&Ks[sr*72 + sc*8 + 32]) = kd1;
      {
        u32 w0[4] = {vd0.x, vd0.y, vd0.z, vd0.w};
        u32 w1[4] = {vd1.x, vd1.y, vd1.z, vd1.w};
        const int ch0 = ((sr>>3) ^ sc)       << 3;
        const int ch1 = ((sr>>3) ^ (sc + 4)) << 3;
        #pragma unroll
        for (int j = 0; j < 8; ++j){
          int d0 = sc*8 + j;
          Vt[d0*72        + ch0 + (sr&7)] = (u16)(w0[j>>1] >> (16*(j&1)));
          Vt[(d0+32)*72   + ch1 + (sr&7)] = (u16)(w1[j>>1] >> (16*(j&1)));
        }
      }
      __syncthreads();             // tile staged

      if (kt + 1 < nkt){           // prefetch next tile during compute
        const u16* srow = stage_base + (size_t)(kt + 1) * 64 * 3072;
        kd0 = *reinterpret_cast<const uint4*>(srow);
        kd1 = *reinterpret_cast<const uint4*>(srow + 32);
        vd0 = *reinterpret_cast<const uint4*>(srow + 128);
        vd1 = *reinterpret_cast<const uint4*>(srow + 160);
      }

      const int kb = kt * 64;

      // ---- S = (Q K^T) * 0.125 ----
      f32x4 s_acc[4] = {};
      #pragma unroll
      for (int f = 0; f < 4; ++f){
        const u16* kp = &Ks[(f*16 + l16)*72 + 8*lhi];
        bf16x8 k0 = *reinterpret_cast<const bf16x8*>(kp);
        bf16x8 k1 = *reinterpret_cast<const bf16x8*>(kp + 32);
        s_acc[f] = mfma16(qf[0], k0, s_acc[f]);
        s_acc[f] = mfma16(qf[1], k1, s_acc[f]);
      }

      float sc_[4][4];
      #pragma unroll
      for (int f = 0; f < 4; ++f){
        #pragma unroll
        for (int r = 0; r < 4; ++r) sc_[f][r] = s_acc[f][r] * 0.125f;
      }

      if (kt == nkt - 1){          // diagonal tile: causal mask
        #pragma unroll
        for (int f = 0; f < 4; ++f){
          int col = kb + f*16 + l16;
          #pragma unroll
          for (int r = 0; r < 4; ++r){
            int row = qrow0 + 4*lhi + r;
            if (col > row) sc_[f][r] = -INFINITY;
          }
        }
      }

      // ---- online softmax (rows live in 16-lane groups) ----
      float alpha[4], p[4][4];
      #pragma unroll
      for (int r = 0; r < 4; ++r){
        float mx = fmaxf(fmaxf(sc_[0][r], sc_[1][r]), fmaxf(sc_[2][r], sc_[3][r]));
        #pragma unroll
        for (int m = 1; m < 16; m <<= 1) mx = fmaxf(mx, __shfl_xor(mx, m, 64));
        float mnew = fmaxf(m_r[r], mx);
        alpha[r] = __expf(m_r[r] - mnew);
        m_r[r] = mnew;
        float sum = 0.0f;
        #pragma unroll
        for (int f = 0; f < 4; ++f){ p[f][r] = __expf(sc_[f][r] - mnew); sum += p[f][r]; }
        #pragma unroll
        for (int m = 1; m < 16; m <<= 1) sum += __shfl_xor(sum, m, 64);
        l_r[r] = l_r[r] * alpha[r] + sum;
      }
      #pragma unroll
      for (int n = 0; n < 4; ++n){
        #pragma unroll
        for (int r = 0; r < 4; ++r) o[n][r] *= alpha[r];
      }

      // ---- P (D-layout) -> per-wave LDS as bf16, read back as A-fragments ----
      #pragma unroll
      for (int f = 0; f < 4; ++f){
        #pragma unroll
        for (int r = 0; r < 4; ++r)
          Ps[wid*1152 + (4*lhi + r)*72 + f*16 + l16] = f2bf(p[f][r]);
      }
      bf16x8 pa[2];
      pa[0] = *reinterpret_cast<const bf16x8*>(&Ps[wid*1152 + l16*72 + 8*lhi]);
      pa[1] = *reinterpret_cast<const bf16x8*>(&Ps[wid*1152 + l16*72 + 8*lhi + 32]);

      // ---- PV: B-fragments are contiguous b128 reads from swizzled-transposed V ----
      #pragma unroll
      for (int n = 0; n < 4; ++n){
        const int dv = n*16 + l16;
        const int dh = dv >> 3;             // = 2n + (l16>>3)
        #pragma unroll
        for (int s = 0; s < 2; ++s){
          const int ch = ((lhi + 4*s) ^ dh) << 3;
          bf16x8 vb = *reinterpret_cast<const bf16x8*>(&Vt[dv*72 + ch]);
          o[n] = mfma16(pa[s], vb, o[n]);
        }
      }
    }

    // ---- store O ----
    float inv_l[4];
    #pragma unroll
    for (int r = 0; r < 4; ++r) inv_l[r] = 1.0f / l_r[r];
    #pragma unroll
    for (int n = 0; n < 4; ++n){
      #pragma unroll
      for (int r = 0; r < 4; ++r){
        int row = qrow0 + 4*lhi + r;
        int col = hh*64 + n*16 + l16;
        att[(size_t)(bb*2048 + row) * 1024 + col] = f2bf(o[n][r] * inv_l[r]);
      }
    }
  }
}

extern "C" void kernel_launch(void* const* d_in, const int* in_sizes, int n_in,
                              void* d_out, int out_size, void* d_ws, size_t ws_size,
                              hipStream_t stream){
  const float* x        = (const float*)d_in[0];
  const float* ln1_w    = (const float*)d_in[1];
  const float* ln1_b    = (const float*)d_in[2];
  const float* c_proj_w = (const float*)d_in[3];
  const float* proj_w   = (const float*)d_in[4];
  const float* proj_b   = (const float*)d_in[5];
  const float* ln2_w    = (const float*)d_in[6];
  const float* ln2_b    = (const float*)d_in[7];
  const float* ffn1_w   = (const float*)d_in[8];
  const float* ffn1_b   = (const float*)d_in[9];
  const float* ffn2_w   = (const float*)d_in[10];
  const float* ffn2_b   = (const float*)d_in[11];

  char* p = (char*)d_ws;
  u16* Wqkv  = (u16*)p;  p += (size_t)3072*1024*2;   // 6.0 MiB
  u16* Wproj = (u16*)p;  p += (size_t)1024*1024*2;   // 2.0 MiB
  u16* Wff1  = (u16*)p;  p += (size_t)4096*1024*2;   // 8.0 MiB
  u16* Wff2  = (u16*)p;  p += (size_t)1024*4096*2;   // 8.0 MiB
  u16* LNb   = (u16*)p;  p += (size_t)4096*1024*2;   // 8.0 MiB (ln1 out, reused for ln2 out)
  u16* QKV   = (u16*)p;  p += (size_t)4096*3072*2;   // 24 MiB
  u16* ATT   = (u16*)p;  p += (size_t)4096*1024*2;   // 8.0 MiB
  float* ACT2= (float*)p;                            // 16 MiB  (total 80 MiB)
  u16* FFN1  = QKV;      // reuse QKV+ATT region (32 MiB) after attention+proj

  cvt_kernel<<<3072, 256, 0, stream>>>(c_proj_w, Wqkv, 786432);
  cvt_kernel<<<1024, 256, 0, stream>>>(proj_w,  Wproj, 262144);
  cvt_kernel<<<4096, 256, 0, stream>>>(ffn1_w,  Wff1, 1048576);
  cvt_kernel<<<4096, 256, 0, stream>>>(ffn2_w,  Wff2, 1048576);

  ln_kernel<<<4096, 256, 0, stream>>>(x, ln1_w, ln1_b, LNb);
  gemm_bt<false,false,false,true ><<<dim3(24,32), 256, 0, stream>>>(LNb, Wqkv, nullptr, nullptr, QKV, 4096, 3072, 1024);
  attn_kernel<<<dim3(16,32), 256, 0, stream>>>(QKV, ATT);
  gemm_bt<true ,true ,false,false><<<dim3(8,32),  256, 0, stream>>>(ATT, Wproj, proj_b, x, ACT2, 4096, 1024, 1024);
  ln_kernel<<<4096, 256, 0, stream>>>(ACT2, ln2_w, ln2_b, LNb);
  gemm_bt<true ,false,true ,true ><<<dim3(32,32), 256, 0, stream>>>(LNb, Wff1, ffn1_b, nullptr, FFN1, 4096, 4096, 1024);
  gemm_bt<true ,true ,false,false><<<dim3(8,32),  256, 0, stream>>>(FFN1, Wff2, ffn2_b, x, (float*)d_out, 4096, 1024, 4096);
}

// Round 7
// 296.946 us; speedup vs baseline: 2.0310x; 1.0547x over previous
//
#include <hip/hip_runtime.h>
#include <math.h>

typedef unsigned short u16;
typedef unsigned int u32;
typedef __attribute__((ext_vector_type(8))) __bf16 bf16x8;
typedef __attribute__((ext_vector_type(4))) float f32x4;

#define DEVI __device__ __forceinline__

DEVI u16 f2bf(float f){
  u32 b = __builtin_bit_cast(u32, f);
  return (u16)((b + 0x7FFFu + ((b >> 16) & 1u)) >> 16);
}

DEVI f32x4 mfma16(bf16x8 a, bf16x8 b, f32x4 c){
  return __builtin_amdgcn_mfma_f32_16x16x32_bf16(a, b, c, 0, 0, 0);
}

// async global->LDS, 16B per lane; LDS dest = wave-uniform base + lane*16.
DEVI void gload16(const u16* g, u16* l){
  __builtin_amdgcn_global_load_lds(
      (const __attribute__((address_space(1))) u32*)g,
      (__attribute__((address_space(3))) u32*)l,
      16, 0, 0);
}

// ---------------- f32 -> bf16 convert (4 elems/thread) ----------------
__global__ __launch_bounds__(256) void cvt_kernel(const float* __restrict__ in,
                                                  u16* __restrict__ out, int n4){
  int i = blockIdx.x * 256 + threadIdx.x;
  if (i >= n4) return;
  float4 v = reinterpret_cast<const float4*>(in)[i];
  u32 lo = (u32)f2bf(v.x) | ((u32)f2bf(v.y) << 16);
  u32 hi = (u32)f2bf(v.z) | ((u32)f2bf(v.w) << 16);
  reinterpret_cast<uint2*>(out)[i] = make_uint2(lo, hi);
}

// ---------------- LayerNorm: f32 in, bf16 out, row length 1024 ----------------
__global__ __launch_bounds__(256) void ln_kernel(const float* __restrict__ x,
                                                 const float* __restrict__ w,
                                                 const float* __restrict__ b,
                                                 u16* __restrict__ out){
  int row = blockIdx.x;
  int tid = threadIdx.x;
  const float4 v = reinterpret_cast<const float4*>(x + (size_t)row * 1024)[tid];
  float s  = v.x + v.y + v.z + v.w;
  float ss = v.x*v.x + v.y*v.y + v.z*v.z + v.w*v.w;
  #pragma unroll
  for (int m = 1; m < 64; m <<= 1){
    s  += __shfl_xor(s,  m, 64);
    ss += __shfl_xor(ss, m, 64);
  }
  __shared__ float red[8];
  int wid = tid >> 6, lane = tid & 63;
  if (lane == 0){ red[wid] = s; red[4 + wid] = ss; }
  __syncthreads();
  s  = red[0] + red[1] + red[2] + red[3];
  ss = red[4] + red[5] + red[6] + red[7];
  float mu   = s * (1.0f/1024.0f);
  float var  = ss * (1.0f/1024.0f) - mu*mu;
  float rstd = rsqrtf(var + 1e-5f);
  const float4 wv = reinterpret_cast<const float4*>(w)[tid];
  const float4 bv = reinterpret_cast<const float4*>(b)[tid];
  u32 lo = (u32)f2bf((v.x-mu)*rstd*wv.x + bv.x) | ((u32)f2bf((v.y-mu)*rstd*wv.y + bv.y) << 16);
  u32 hi = (u32)f2bf((v.z-mu)*rstd*wv.z + bv.z) | ((u32)f2bf((v.w-mu)*rstd*wv.w + bv.w) << 16);
  reinterpret_cast<uint2*>(out + (size_t)row*1024)[tid] = make_uint2(lo, hi);
}

// ---------------- GEMM: C(MxN) = A(MxK) * W(NxK)^T (+bias)(+relu)(+res) ----------------
// 256 thr / 4 waves, block tile 128x128, wave tile 64x64, BK=32.
// Double-buffered LDS: stage tile k+1 (global_load_lds x4/wave) right after the
// barrier, then compute tile k -> ONE __syncthreads per K-step; its vmcnt(0)
// drain waits on loads issued a full iteration earlier (latency hidden).
// XCD chunked swizzle: contiguous run of row-major tiles per XCD (A-panel L2 reuse).
template<bool HAS_BIAS, bool HAS_RES, bool RELU, bool OUT_BF16>
__global__ __launch_bounds__(256) void gemm_bt(const u16* __restrict__ A,
                                               const u16* __restrict__ W,
                                               const float* __restrict__ bias,
                                               const float* __restrict__ res,
                                               void* __restrict__ outp,
                                               int M, int N, int K){
  const int tid = threadIdx.x;
  const int wid = tid >> 6, lane = tid & 63;
  const int l16 = lane & 15, lhi = lane >> 4;
  const int wr = wid >> 1, wc = wid & 1;

  // XCD-aware bijective swizzle (grid size divisible by 8 for all our shapes)
  const int gx = gridDim.x;
  const int nwg = gx * gridDim.y;
  const int bid = blockIdx.y * gx + blockIdx.x;
  const int swz = (bid & 7) * (nwg >> 3) + (bid >> 3);
  const int brow = (swz / gx) * 128;
  const int bcol = (swz % gx) * 128;

  __shared__ u16 As[2][128*32];
  __shared__ u16 Bs[2][128*32];

  const int srow = wid*32 + (lane >> 2);
  const int schk = lane & 3;
  const u16* gA0 = A + (size_t)(brow + srow)      * K + schk*8;
  const u16* gA1 = A + (size_t)(brow + srow + 16) * K + schk*8;
  const u16* gW0 = W + (size_t)(bcol + srow)      * K + schk*8;
  const u16* gW1 = W + (size_t)(bcol + srow + 16) * K + schk*8;
  const int ldsA0 = (wid*32)*32, ldsA1 = (wid*32 + 16)*32;

  f32x4 acc[4][4] = {};

  // prologue: stage tile 0 into buffer 0
  gload16(gA0, &As[0][ldsA0]);
  gload16(gA1, &As[0][ldsA1]);
  gload16(gW0, &Bs[0][ldsA0]);
  gload16(gW1, &Bs[0][ldsA1]);

  int cur = 0;
  for (int k0 = 0; k0 < K; k0 += 32){
    __syncthreads();       // stage(cur) landed (vmcnt drain); prev-tile reads done
    if (k0 + 32 < K){      // stage next tile into the other buffer
      gload16(gA0 + k0 + 32, &As[cur^1][ldsA0]);
      gload16(gA1 + k0 + 32, &As[cur^1][ldsA1]);
      gload16(gW0 + k0 + 32, &Bs[cur^1][ldsA0]);
      gload16(gW1 + k0 + 32, &Bs[cur^1][ldsA1]);
    }
    bf16x8 af[4], bfr[4];
    #pragma unroll
    for (int m = 0; m < 4; ++m)
      af[m]  = *reinterpret_cast<const bf16x8*>(&As[cur][(wr*64 + m*16 + l16)*32 + 8*lhi]);
    #pragma unroll
    for (int n = 0; n < 4; ++n)
      bfr[n] = *reinterpret_cast<const bf16x8*>(&Bs[cur][(wc*64 + n*16 + l16)*32 + 8*lhi]);
    #pragma unroll
    for (int m = 0; m < 4; ++m){
      #pragma unroll
      for (int n = 0; n < 4; ++n){
        acc[m][n] = mfma16(af[m], bfr[n], acc[m][n]);
      }
    }
    cur ^= 1;
  }

  const int row0 = brow + wr*64;
  const int col0 = bcol + wc*64;
  #pragma unroll
  for (int m = 0; m < 4; ++m){
    #pragma unroll
    for (int n = 0; n < 4; ++n){
      #pragma unroll
      for (int r = 0; r < 4; ++r){
        int row = row0 + m*16 + 4*lhi + r;
        int col = col0 + n*16 + l16;
        float v = acc[m][n][r];
        if constexpr (HAS_BIAS) v += bias[col];
        if constexpr (RELU)     v = fmaxf(v, 0.0f);
        if constexpr (HAS_RES)  v += res[(size_t)row * N + col];
        if constexpr (OUT_BF16) ((u16*)outp)[(size_t)row * N + col] = f2bf(v);
        else                    ((float*)outp)[(size_t)row * N + col] = v;
      }
    }
  }
}

// ---------------- causal flash attention (paired LPT + prefetch, R3 dataflow) -------
// (unchanged from round 6 — passing, no longer top-5)
__global__ __launch_bounds__(256) void attn_kernel(const u16* __restrict__ qkv,
                                                   u16* __restrict__ att){
  const int bx = blockIdx.x;            // handles qt = bx and 31-bx (33 tiles total)
  const int bh = blockIdx.y;
  const int bb = bh >> 4, hh = bh & 15;
  const int tid = threadIdx.x;
  const int wid = tid >> 6, lane = tid & 63;
  const int l16 = lane & 15, lhi = lane >> 4;
  const u16* base = qkv + (size_t)bb * 2048 * 3072 + (size_t)hh * 192;

  __shared__ u16 Ks[64*72];
  __shared__ u16 Vt[64*72];
  __shared__ u16 Ps[4*16*72];

  const int sr = tid >> 2;
  const int sc = tid & 3;
  const u16* stage_base = base + (size_t)sr * 3072 + sc*8;   // K at +0, V at +128

  for (int ph = 0; ph < 2; ++ph){
    const int qt = ph ? (31 - bx) : bx;
    const int qrow0 = qt * 64 + wid * 16;

    bf16x8 qf[2];
    {
      const u16* qp = base + (size_t)(qrow0 + l16) * 3072 + 64 + 8*lhi;
      qf[0] = *reinterpret_cast<const bf16x8*>(qp);
      qf[1] = *reinterpret_cast<const bf16x8*>(qp + 32);
    }

    f32x4 o[4] = {};
    float m_r[4], l_r[4];
    #pragma unroll
    for (int r = 0; r < 4; ++r){ m_r[r] = -INFINITY; l_r[r] = 0.0f; }

    const int nkt = qt + 1;

    uint4 kd0, kd1, vd0, vd1;
    {
      const u16* srow = stage_base;
      kd0 = *reinterpret_cast<const uint4*>(srow);
      kd1 = *reinterpret_cast<const uint4*>(srow + 32);
      vd0 = *reinterpret_cast<const uint4*>(srow + 128);
      vd1 = *reinterpret_cast<const uint4*>(srow + 160);
    }

    for (int kt = 0; kt < nkt; ++kt){
      __syncthreads();
      *reinterpret_cast<uint4*>(&Ks[sr*72 + sc*8])      = kd0;
      *reinterpret_cast<uint4*>(&Ks[sr*72 + sc*8 + 32]) = kd1;
      {
        u32 w0[4] = {vd0.x, vd0.y, vd0.z, vd0.w};
        u32 w1[4] = {vd1.x, vd1.y, vd1.z, vd1.w};
        const int ch0 = ((sr>>3) ^ sc)       << 3;
        const int ch1 = ((sr>>3) ^ (sc + 4)) << 3;
        #pragma unroll
        for (int j = 0; j < 8; ++j){
          int d0 = sc*8 + j;
          Vt[d0*72        + ch0 + (sr&7)] = (u16)(w0[j>>1] >> (16*(j&1)));
          Vt[(d0+32)*72   + ch1 + (sr&7)] = (u16)(w1[j>>1] >> (16*(j&1)));
        }
      }
      __syncthreads();

      if (kt + 1 < nkt){
        const u16* srow = stage_base + (size_t)(kt + 1) * 64 * 3072;
        kd0 = *reinterpret_cast<const uint4*>(srow);
        kd1 = *reinterpret_cast<const uint4*>(srow + 32);
        vd0 = *reinterpret_cast<const uint4*>(srow + 128);
        vd1 = *reinterpret_cast<const uint4*>(srow + 160);
      }

      const int kb = kt * 64;

      f32x4 s_acc[4] = {};
      #pragma unroll
      for (int f = 0; f < 4; ++f){
        const u16* kp = &Ks[(f*16 + l16)*72 + 8*lhi];
        bf16x8 k0 = *reinterpret_cast<const bf16x8*>(kp);
        bf16x8 k1 = *reinterpret_cast<const bf16x8*>(kp + 32);
        s_acc[f] = mfma16(qf[0], k0, s_acc[f]);
        s_acc[f] = mfma16(qf[1], k1, s_acc[f]);
      }

      float sc_[4][4];
      #pragma unroll
      for (int f = 0; f < 4; ++f){
        #pragma unroll
        for (int r = 0; r < 4; ++r) sc_[f][r] = s_acc[f][r] * 0.125f;
      }

      if (kt == nkt - 1){
        #pragma unroll
        for (int f = 0; f < 4; ++f){
          int col = kb + f*16 + l16;
          #pragma unroll
          for (int r = 0; r < 4; ++r){
            int row = qrow0 + 4*lhi + r;
            if (col > row) sc_[f][r] = -INFINITY;
          }
        }
      }

      float alpha[4], p[4][4];
      #pragma unroll
      for (int r = 0; r < 4; ++r){
        float mx = fmaxf(fmaxf(sc_[0][r], sc_[1][r]), fmaxf(sc_[2][r], sc_[3][r]));
        #pragma unroll
        for (int m = 1; m < 16; m <<= 1) mx = fmaxf(mx, __shfl_xor(mx, m, 64));
        float mnew = fmaxf(m_r[r], mx);
        alpha[r] = __expf(m_r[r] - mnew);
        m_r[r] = mnew;
        float sum = 0.0f;
        #pragma unroll
        for (int f = 0; f < 4; ++f){ p[f][r] = __expf(sc_[f][r] - mnew); sum += p[f][r]; }
        #pragma unroll
        for (int m = 1; m < 16; m <<= 1) sum += __shfl_xor(sum, m, 64);
        l_r[r] = l_r[r] * alpha[r] + sum;
      }
      #pragma unroll
      for (int n = 0; n < 4; ++n){
        #pragma unroll
        for (int r = 0; r < 4; ++r) o[n][r] *= alpha[r];
      }

      #pragma unroll
      for (int f = 0; f < 4; ++f){
        #pragma unroll
        for (int r = 0; r < 4; ++r)
          Ps[wid*1152 + (4*lhi + r)*72 + f*16 + l16] = f2bf(p[f][r]);
      }
      bf16x8 pa[2];
      pa[0] = *reinterpret_cast<const bf16x8*>(&Ps[wid*1152 + l16*72 + 8*lhi]);
      pa[1] = *reinterpret_cast<const bf16x8*>(&Ps[wid*1152 + l16*72 + 8*lhi + 32]);

      #pragma unroll
      for (int n = 0; n < 4; ++n){
        const int dv = n*16 + l16;
        const int dh = dv >> 3;
        #pragma unroll
        for (int s = 0; s < 2; ++s){
          const int ch = ((lhi + 4*s) ^ dh) << 3;
          bf16x8 vb = *reinterpret_cast<const bf16x8*>(&Vt[dv*72 + ch]);
          o[n] = mfma16(pa[s], vb, o[n]);
        }
      }
    }

    float inv_l[4];
    #pragma unroll
    for (int r = 0; r < 4; ++r) inv_l[r] = 1.0f / l_r[r];
    #pragma unroll
    for (int n = 0; n < 4; ++n){
      #pragma unroll
      for (int r = 0; r < 4; ++r){
        int row = qrow0 + 4*lhi + r;
        int col = hh*64 + n*16 + l16;
        att[(size_t)(bb*2048 + row) * 1024 + col] = f2bf(o[n][r] * inv_l[r]);
      }
    }
  }
}

extern "C" void kernel_launch(void* const* d_in, const int* in_sizes, int n_in,
                              void* d_out, int out_size, void* d_ws, size_t ws_size,
                              hipStream_t stream){
  const float* x        = (const float*)d_in[0];
  const float* ln1_w    = (const float*)d_in[1];
  const float* ln1_b    = (const float*)d_in[2];
  const float* c_proj_w = (const float*)d_in[3];
  const float* proj_w   = (const float*)d_in[4];
  const float* proj_b   = (const float*)d_in[5];
  const float* ln2_w    = (const float*)d_in[6];
  const float* ln2_b    = (const float*)d_in[7];
  const float* ffn1_w   = (const float*)d_in[8];
  const float* ffn1_b   = (const float*)d_in[9];
  const float* ffn2_w   = (const float*)d_in[10];
  const float* ffn2_b   = (const float*)d_in[11];

  char* p = (char*)d_ws;
  u16* Wqkv  = (u16*)p;  p += (size_t)3072*1024*2;   // 6.0 MiB
  u16* Wproj = (u16*)p;  p += (size_t)1024*1024*2;   // 2.0 MiB
  u16* Wff1  = (u16*)p;  p += (size_t)4096*1024*2;   // 8.0 MiB
  u16* Wff2  = (u16*)p;  p += (size_t)1024*4096*2;   // 8.0 MiB
  u16* LNb   = (u16*)p;  p += (size_t)4096*1024*2;   // 8.0 MiB (ln1 out, reused for ln2 out)
  u16* QKV   = (u16*)p;  p += (size_t)4096*3072*2;   // 24 MiB
  u16* ATT   = (u16*)p;  p += (size_t)4096*1024*2;   // 8.0 MiB
  float* ACT2= (float*)p;                            // 16 MiB  (total 80 MiB)
  u16* FFN1  = QKV;      // reuse QKV+ATT region (32 MiB) after attention+proj

  cvt_kernel<<<3072, 256, 0, stream>>>(c_proj_w, Wqkv, 786432);
  cvt_kernel<<<1024, 256, 0, stream>>>(proj_w,  Wproj, 262144);
  cvt_kernel<<<4096, 256, 0, stream>>>(ffn1_w,  Wff1, 1048576);
  cvt_kernel<<<4096, 256, 0, stream>>>(ffn2_w,  Wff2, 1048576);

  ln_kernel<<<4096, 256, 0, stream>>>(x, ln1_w, ln1_b, LNb);
  gemm_bt<false,false,false,true ><<<dim3(24,32), 256, 0, stream>>>(LNb, Wqkv, nullptr, nullptr, QKV, 4096, 3072, 1024);
  attn_kernel<<<dim3(16,32), 256, 0, stream>>>(QKV, ATT);
  gemm_bt<true ,true ,false,false><<<dim3(8,32),  256, 0, stream>>>(ATT, Wproj, proj_b, x, ACT2, 4096, 1024, 1024);
  ln_kernel<<<4096, 256, 0, stream>>>(ACT2, ln2_w, ln2_b, LNb);
  gemm_bt<true ,false,true ,true ><<<dim3(32,32), 256, 0, stream>>>(LNb, Wff1, ffn1_b, nullptr, FFN1, 4096, 4096, 1024);
  gemm_bt<true ,true ,false,false><<<dim3(8,32),  256, 0, stream>>>(FFN1, Wff2, ffn2_b, x, (float*)d_out, 4096, 1024, 4096);
}